// Round 2
// baseline (403.341 us; speedup 1.0000x reference)
//
#include <hip/hip_runtime.h>
#include <math.h>

// ============================================================
// Small dense linear algebra in double precision (per-thread).
// 9x9 symmetric stored packed lower-tri: M[i*(i+1)/2 + j], j<=i.
// ============================================================

__device__ __forceinline__ void chol9(double* M) {
#pragma unroll
  for (int i = 0; i < 9; ++i) {
    const int ib = i * (i + 1) / 2;
#pragma unroll
    for (int j = 0; j <= i; ++j) {
      const int jb = j * (j + 1) / 2;
      double s = M[ib + j];
#pragma unroll
      for (int k = 0; k < j; ++k) s -= M[ib + k] * M[jb + k];
      if (j == i)
        M[ib + j] = sqrt(fmax(s, 1e-300));
      else
        M[ib + j] = s / M[jb + j];
    }
  }
}

__device__ __forceinline__ void cholsolve9(const double* L, double* x) {
#pragma unroll
  for (int i = 0; i < 9; ++i) {
    const int ib = i * (i + 1) / 2;
    double s = x[i];
#pragma unroll
    for (int k = 0; k < i; ++k) s -= L[ib + k] * x[k];
    x[i] = s / L[ib + i];
  }
#pragma unroll
  for (int i = 8; i >= 0; --i) {
    double s = x[i];
#pragma unroll
    for (int k = i + 1; k < 9; ++k) s -= L[k * (k + 1) / 2 + i] * x[k];
    x[i] = s / L[i * (i + 1) / 2 + i];
  }
}

// Smallest-eigenvalue eigenvector of symmetric 3x3 via cyclic Jacobi.
// 6 sweeps: quadratic convergence -> machine eps well before that.
__device__ __forceinline__ void smallest_evec3(const double G[3][3], double v3[3]) {
  double a[3][3] = {{G[0][0], G[0][1], G[0][2]},
                    {G[1][0], G[1][1], G[1][2]},
                    {G[2][0], G[2][1], G[2][2]}};
  double V[3][3] = {{1, 0, 0}, {0, 1, 0}, {0, 0, 1}};
  for (int sweep = 0; sweep < 6; ++sweep) {
#pragma unroll
    for (int p = 0; p < 2; ++p) {
#pragma unroll
      for (int q = p + 1; q < 3; ++q) {
        double apq = a[p][q];
        if (fabs(apq) < 1e-300) continue;
        double tau = (a[q][q] - a[p][p]) / (2.0 * apq);
        double t = ((tau >= 0.0) ? 1.0 : -1.0) / (fabs(tau) + sqrt(1.0 + tau * tau));
        double c = 1.0 / sqrt(1.0 + t * t);
        double s = t * c;
#pragma unroll
        for (int k = 0; k < 3; ++k) {  // A = A*J
          double akp = a[k][p], akq = a[k][q];
          a[k][p] = c * akp - s * akq;
          a[k][q] = s * akp + c * akq;
        }
#pragma unroll
        for (int k = 0; k < 3; ++k) {  // A = J^T*A
          double apk = a[p][k], aqk = a[q][k];
          a[p][k] = c * apk - s * aqk;
          a[q][k] = s * apk + c * aqk;
        }
#pragma unroll
        for (int k = 0; k < 3; ++k) {  // V = V*J
          double vkp = V[k][p], vkq = V[k][q];
          V[k][p] = c * vkp - s * vkq;
          V[k][q] = s * vkp + c * vkq;
        }
      }
    }
  }
  double mv = a[0][0];
  double v0 = V[0][0], v1 = V[1][0], v2 = V[2][0];
  if (a[1][1] < mv) { mv = a[1][1]; v0 = V[0][1]; v1 = V[1][1]; v2 = V[2][1]; }
  if (a[2][2] < mv) { mv = a[2][2]; v0 = V[0][2]; v1 = V[1][2]; v2 = V[2][2]; }
  v3[0] = v0; v3[1] = v1; v3[2] = v2;
}

// From accumulated AtA (packed, destroyed) + normalization params -> F (9 floats).
__device__ __forceinline__ void solveF(double* M, double s1, double m1x, double m1y,
                                       double s2, double m2x, double m2y,
                                       float* out) {
  double tr = M[0] + M[2] + M[5] + M[9] + M[14] + M[20] + M[27] + M[35] + M[44];
  double shift = 1e-12 * tr;
  M[0] += shift; M[2] += shift; M[5] += shift; M[9] += shift; M[14] += shift;
  M[20] += shift; M[27] += shift; M[35] += shift; M[44] += shift;
  chol9(M);
  double x[9];
#pragma unroll
  for (int i = 0; i < 9; ++i) x[i] = 1.0;
  // inverse iteration: gain per iter ~ lam2/lam1 ~ 1e12 -> 3 iters is overkill-safe
  for (int t = 0; t < 3; ++t) {
    cholsolve9(M, x);
    double n = 0.0;
#pragma unroll
    for (int i = 0; i < 9; ++i) n += x[i] * x[i];
    n = 1.0 / sqrt(n);
#pragma unroll
    for (int i = 0; i < 9; ++i) x[i] *= n;
  }
  double F0[3][3] = {{x[0], x[1], x[2]}, {x[3], x[4], x[5]}, {x[6], x[7], x[8]}};
  double G[3][3];
#pragma unroll
  for (int i = 0; i < 3; ++i)
#pragma unroll
    for (int j = 0; j < 3; ++j)
      G[i][j] = F0[0][i] * F0[0][j] + F0[1][i] * F0[1][j] + F0[2][i] * F0[2][j];
  double v3[3];
  smallest_evec3(G, v3);
  double Fv[3];
#pragma unroll
  for (int i = 0; i < 3; ++i)
    Fv[i] = F0[i][0] * v3[0] + F0[i][1] * v3[1] + F0[i][2] * v3[2];
  double F2[3][3];
#pragma unroll
  for (int i = 0; i < 3; ++i)
#pragma unroll
    for (int j = 0; j < 3; ++j) F2[i][j] = F0[i][j] - Fv[i] * v3[j];
  double R[3][3];
#pragma unroll
  for (int j = 0; j < 3; ++j) {
    R[0][j] = s2 * F2[0][j];
    R[1][j] = s2 * F2[1][j];
    R[2][j] = -s2 * m2x * F2[0][j] - s2 * m2y * F2[1][j] + F2[2][j];
  }
  double Ff[3][3];
#pragma unroll
  for (int i = 0; i < 3; ++i) {
    Ff[i][0] = s1 * R[i][0];
    Ff[i][1] = s1 * R[i][1];
    Ff[i][2] = -s1 * m1x * R[i][0] - s1 * m1y * R[i][1] + R[i][2];
  }
  double inv = 1.0 / Ff[2][2];
#pragma unroll
  for (int i = 0; i < 3; ++i)
#pragma unroll
    for (int j = 0; j < 3; ++j) out[3 * i + j] = (float)(Ff[i][j] * inv);
}

// ============================================================
// Kernel 0: AoS -> SoA transpose of the point arrays (coalesced consumers)
// ============================================================
__global__ __launch_bounds__(256) void transpose_soa(
    const float* __restrict__ p1, const float* __restrict__ p2,
    float* __restrict__ x1, float* __restrict__ y1, float* __restrict__ z1,
    float* __restrict__ x2, float* __restrict__ y2, float* __restrict__ z2,
    int N) {
  const int i = blockIdx.x * 256 + threadIdx.x;
  if (i >= N) return;
  x1[i] = p1[3 * i]; y1[i] = p1[3 * i + 1]; z1[i] = p1[3 * i + 2];
  x2[i] = p2[3 * i]; y2[i] = p2[3 * i + 1]; z2[i] = p2[3 * i + 2];
}

// ============================================================
// Kernel 1: one thread per RANSAC iteration -> model F (9 floats) + uniq flag
// ============================================================
__global__ __launch_bounds__(64) void fit_models(
    const float* __restrict__ pts1, const float* __restrict__ pts2,
    const int* __restrict__ samples, float* __restrict__ models,
    int* __restrict__ uflag, int iters) {
  const int it = blockIdx.x * 64 + threadIdx.x;
  if (it >= iters) return;
  int idx[8];
#pragma unroll
  for (int k = 0; k < 8; ++k) idx[k] = samples[it * 8 + k];
  int u = 1;
#pragma unroll
  for (int a = 0; a < 8; ++a)
#pragma unroll
    for (int b = a + 1; b < 8; ++b)
      if (idx[a] == idx[b]) u = 0;
  uflag[it] = u;

  float X1[8], Y1[8], Z1[8], X2[8], Y2[8], Z2[8];
#pragma unroll
  for (int k = 0; k < 8; ++k) {
    const int j = idx[k];
    X1[k] = pts1[3 * j];     Y1[k] = pts1[3 * j + 1]; Z1[k] = pts1[3 * j + 2];
    X2[k] = pts2[3 * j];     Y2[k] = pts2[3 * j + 1]; Z2[k] = pts2[3 * j + 2];
  }
  double sx1 = 0, sy1 = 0, sx2 = 0, sy2 = 0;
#pragma unroll
  for (int k = 0; k < 8; ++k) {
    sx1 += (double)X1[k]; sy1 += (double)Y1[k];
    sx2 += (double)X2[k]; sy2 += (double)Y2[k];
  }
  const double m1x = sx1 / 8.0, m1y = sy1 / 8.0;
  const double m2x = sx2 / 8.0, m2y = sy2 / 8.0;
  double sd1 = 0, sd2 = 0;
#pragma unroll
  for (int k = 0; k < 8; ++k) {
    double dx1 = (double)X1[k] - m1x, dy1 = (double)Y1[k] - m1y;
    double dx2 = (double)X2[k] - m2x, dy2 = (double)Y2[k] - m2y;
    sd1 += sqrt(dx1 * dx1 + dy1 * dy1);
    sd2 += sqrt(dx2 * dx2 + dy2 * dy2);
  }
  const double s1 = sqrt(2.0) / (sd1 / 8.0 + 1e-8);
  const double s2 = sqrt(2.0) / (sd2 / 8.0 + 1e-8);

  double M[45];
#pragma unroll
  for (int r = 0; r < 45; ++r) M[r] = 0.0;
#pragma unroll
  for (int k = 0; k < 8; ++k) {
    const double z1 = (double)Z1[k], z2 = (double)Z2[k];
    const double p1x = s1 * ((double)X1[k] - m1x * z1);
    const double p1y = s1 * ((double)Y1[k] - m1y * z1);
    const double p2x = s2 * ((double)X2[k] - m2x * z2);
    const double p2y = s2 * ((double)Y2[k] - m2y * z2);
    const double a[9] = {p2x * p1x, p2x * p1y, p2x * z1,
                         p2y * p1x, p2y * p1y, p2y * z1,
                         z2 * p1x,  z2 * p1y,  z2 * z1};
#pragma unroll
    for (int i = 0; i < 9; ++i)
#pragma unroll
      for (int j = 0; j <= i; ++j) M[i * (i + 1) / 2 + j] += a[i] * a[j];
  }
  solveF(M, s1, m1x, m1y, s2, m2x, m2y, models + (size_t)it * 9);
}

// ============================================================
// Sampson error (fp32, identical op order to R0 — do not perturb mask bits)
// ============================================================
__device__ __forceinline__ float sampson_err(const float* __restrict__ F,
                                             float x1, float y1, float z1,
                                             float x2, float y2, float z2) {
  float a0 = F[0] * x1 + F[1] * y1 + F[2] * z1;
  float a1 = F[3] * x1 + F[4] * y1 + F[5] * z1;
  float a2 = F[6] * x1 + F[7] * y1 + F[8] * z1;
  float b0 = F[0] * x2 + F[3] * y2 + F[6] * z2;
  float b1 = F[1] * x2 + F[4] * y2 + F[7] * z2;
  float d = x2 * a0 + y2 * a1 + z2 * a2;
  float den = a0 * a0 + a1 * a1 + b0 * b0 + b1 * b1;
  return (d * d) / den;
}

// Kernel 2: 4 models per block; inlier count + sum(sqrt(err)) over all points.
// SoA point loads are fully coalesced; point reads amortized over 4 models.
__global__ __launch_bounds__(256) void sampson_stats4(
    const float* __restrict__ x1, const float* __restrict__ y1,
    const float* __restrict__ z1, const float* __restrict__ x2,
    const float* __restrict__ y2, const float* __restrict__ z2,
    const float* __restrict__ models, float* __restrict__ ml,
    float* __restrict__ ssum, int N, int iters) {
  const int m0 = blockIdx.x * 4;
  float F[4][9];
#pragma unroll
  for (int m = 0; m < 4; ++m)
#pragma unroll
    for (int r = 0; r < 9; ++r)
      F[m][r] = (m0 + m < iters) ? models[(size_t)(m0 + m) * 9 + r] : 0.f;
  float cnt[4] = {0, 0, 0, 0}, ss[4] = {0, 0, 0, 0};
  for (int i = threadIdx.x; i < N; i += 256) {
    const float a = x1[i], b = y1[i], c = z1[i];
    const float d = x2[i], e = y2[i], f = z2[i];
#pragma unroll
    for (int m = 0; m < 4; ++m) {
      float err = sampson_err(F[m], a, b, c, d, e, f);
      if (err <= 1.0f) {
        cnt[m] += 1.0f;
        ss[m] += sqrtf(err);
      }
    }
  }
  __shared__ float sc[4][4], sv[4][4];
  const int lane = threadIdx.x & 63, wv = threadIdx.x >> 6;
#pragma unroll
  for (int m = 0; m < 4; ++m) {
    float c = cnt[m], s = ss[m];
#pragma unroll
    for (int o = 32; o > 0; o >>= 1) {
      c += __shfl_down(c, o);
      s += __shfl_down(s, o);
    }
    if (lane == 0) { sc[wv][m] = c; sv[wv][m] = s; }
  }
  __syncthreads();
  if (threadIdx.x < 4 && m0 + threadIdx.x < iters) {
    const int m = threadIdx.x;
    ml[m0 + m] = sc[0][m] + sc[1][m] + sc[2][m] + sc[3][m];
    ssum[m0 + m] = sv[0][m] + sv[1][m] + sv[2][m] + sv[3][m];
  }
}

// ============================================================
// Kernel 3: scores + argmax (first-index tie-break like jnp.argmax)
// ============================================================
__global__ __launch_bounds__(256) void select_best(
    const float* __restrict__ ml, const float* __restrict__ ssum,
    const int* __restrict__ uniq, int iters, int* __restrict__ best) {
  const int tid = threadIdx.x;
  __shared__ float ra[256], rb[256];
  __shared__ int rid[256];
  float mlmax = 0.f, mnmax = -INFINITY;
  for (int i = tid; i < iters; i += 256) {
    if (uniq[i]) {
      float m = ml[i];
      mlmax = fmaxf(mlmax, m);
      float mean = (ssum[i] + 1e-8f) / (m + 1e-8f);
      mnmax = fmaxf(mnmax, mean);
    }
  }
  ra[tid] = mlmax;
  rb[tid] = mnmax;
  __syncthreads();
  for (int s = 128; s > 0; s >>= 1) {
    if (tid < s) {
      ra[tid] = fmaxf(ra[tid], ra[tid + s]);
      rb[tid] = fmaxf(rb[tid], rb[tid + s]);
    }
    __syncthreads();
  }
  const float MLMAX = ra[0];
  const float MNMAX = rb[0];
  __syncthreads();
  float bsc = -INFINITY;
  int bid = 0x7FFFFFFF;
  for (int i = tid; i < iters; i += 256) {
    float sc = -INFINITY;
    float m = ml[i];
    float mean = (ssum[i] + 1e-8f) / (m + 1e-8f);
    if (uniq[i]) sc = 0.5f * (m / MLMAX) + 0.5f * (1.0f - mean / MNMAX);
    if (sc > bsc || (sc == bsc && i < bid)) { bsc = sc; bid = i; }
  }
  ra[tid] = bsc;
  rid[tid] = bid;
  __syncthreads();
  for (int s = 128; s > 0; s >>= 1) {
    if (tid < s) {
      if (ra[tid + s] > ra[tid] ||
          (ra[tid + s] == ra[tid] && rid[tid + s] < rid[tid])) {
        ra[tid] = ra[tid + s];
        rid[tid] = rid[tid + s];
      }
    }
    __syncthreads();
  }
  if (tid == 0) best[0] = rid[0];
}

// ============================================================
// Kernel 4: best model's inlier mask to d_out[9..9+N)  (SoA, coalesced)
// ============================================================
__global__ __launch_bounds__(256) void write_mask(
    const float* __restrict__ x1, const float* __restrict__ y1,
    const float* __restrict__ z1, const float* __restrict__ x2,
    const float* __restrict__ y2, const float* __restrict__ z2,
    const float* __restrict__ models, const int* __restrict__ best,
    float* __restrict__ outmask, int N) {
  const int i = blockIdx.x * 256 + threadIdx.x;
  if (i >= N) return;
  const float* F = models + (size_t)best[0] * 9;
  float err = sampson_err(F, x1[i], y1[i], z1[i], x2[i], y2[i], z2[i]);
  outmask[i] = (err <= 1.0f) ? 1.0f : 0.0f;
}

// ============================================================
// Final fit, grid-parallel. Accumulator layout in acc (doubles):
// [0]=sw [1]=sx1 [2]=sy1 [3]=sx2 [4]=sy2 [5]=sd1 [6]=sd2 [7..51]=AtA(45)
// ============================================================
__global__ __launch_bounds__(256) void ff_pass1(
    const float* __restrict__ mask, const float* __restrict__ x1,
    const float* __restrict__ y1, const float* __restrict__ x2,
    const float* __restrict__ y2, double* __restrict__ acc, int N) {
  const int i = blockIdx.x * 256 + threadIdx.x;
  double w = 0, a = 0, b = 0, c = 0, d = 0;
  if (i < N) {
    w = (double)mask[i];
    a = w * (double)x1[i];
    b = w * (double)y1[i];
    c = w * (double)x2[i];
    d = w * (double)y2[i];
  }
#pragma unroll
  for (int o = 32; o > 0; o >>= 1) {
    w += __shfl_down(w, o); a += __shfl_down(a, o); b += __shfl_down(b, o);
    c += __shfl_down(c, o); d += __shfl_down(d, o);
  }
  if ((threadIdx.x & 63) == 0) {
    atomicAdd(&acc[0], w); atomicAdd(&acc[1], a); atomicAdd(&acc[2], b);
    atomicAdd(&acc[3], c); atomicAdd(&acc[4], d);
  }
}

__global__ __launch_bounds__(256) void ff_pass2(
    const float* __restrict__ mask, const float* __restrict__ x1,
    const float* __restrict__ y1, const float* __restrict__ x2,
    const float* __restrict__ y2, double* __restrict__ acc, int N) {
  const double WS = acc[0];
  const double M1X = acc[1] / WS, M1Y = acc[2] / WS;
  const double M2X = acc[3] / WS, M2Y = acc[4] / WS;
  const int i = blockIdx.x * 256 + threadIdx.x;
  double s1 = 0, s2 = 0;
  if (i < N) {
    double w = (double)mask[i];
    if (w != 0.0) {
      double dx1 = (double)x1[i] - M1X, dy1 = (double)y1[i] - M1Y;
      double dx2 = (double)x2[i] - M2X, dy2 = (double)y2[i] - M2Y;
      s1 = w * sqrt(dx1 * dx1 + dy1 * dy1);
      s2 = w * sqrt(dx2 * dx2 + dy2 * dy2);
    }
  }
#pragma unroll
  for (int o = 32; o > 0; o >>= 1) {
    s1 += __shfl_down(s1, o);
    s2 += __shfl_down(s2, o);
  }
  if ((threadIdx.x & 63) == 0) {
    atomicAdd(&acc[5], s1);
    atomicAdd(&acc[6], s2);
  }
}

// each thread handles 4 points; per-wave reduce the 45 AtA entries, then atomics
__global__ __launch_bounds__(256) void ff_pass3(
    const float* __restrict__ mask, const float* __restrict__ x1,
    const float* __restrict__ y1, const float* __restrict__ z1,
    const float* __restrict__ x2, const float* __restrict__ y2,
    const float* __restrict__ z2, double* __restrict__ acc, int N) {
  const double WS = acc[0];
  const double M1X = acc[1] / WS, M1Y = acc[2] / WS;
  const double M2X = acc[3] / WS, M2Y = acc[4] / WS;
  const double S1 = sqrt(2.0) / (acc[5] / WS + 1e-8);
  const double S2 = sqrt(2.0) / (acc[6] / WS + 1e-8);
  double A[45];
#pragma unroll
  for (int r = 0; r < 45; ++r) A[r] = 0.0;
#pragma unroll
  for (int k = 0; k < 4; ++k) {
    const int i = blockIdx.x * 1024 + k * 256 + threadIdx.x;
    if (i < N) {
      const double w = (double)mask[i];
      if (w != 0.0) {
        const double zz1 = (double)z1[i], zz2 = (double)z2[i];
        const double p1x = S1 * ((double)x1[i] - M1X * zz1);
        const double p1y = S1 * ((double)y1[i] - M1Y * zz1);
        const double p2x = S2 * ((double)x2[i] - M2X * zz2);
        const double p2y = S2 * ((double)y2[i] - M2Y * zz2);
        const double a[9] = {p2x * p1x, p2x * p1y, p2x * zz1,
                             p2y * p1x, p2y * p1y, p2y * zz1,
                             zz2 * p1x, zz2 * p1y, zz2 * zz1};
        const double ww = w * w;
#pragma unroll
        for (int ii = 0; ii < 9; ++ii)
#pragma unroll
          for (int jj = 0; jj <= ii; ++jj)
            A[ii * (ii + 1) / 2 + jj] += ww * a[ii] * a[jj];
      }
    }
  }
  const int lane = threadIdx.x & 63;
#pragma unroll
  for (int r = 0; r < 45; ++r) {
    double v = A[r];
#pragma unroll
    for (int o = 32; o > 0; o >>= 1) v += __shfl_down(v, o);
    if (lane == 0) atomicAdd(&acc[7 + r], v);
  }
}

__global__ __launch_bounds__(64) void ff_solve(const double* __restrict__ acc,
                                               float* __restrict__ outF) {
  if (threadIdx.x != 0 || blockIdx.x != 0) return;
  const double WS = acc[0];
  const double M1X = acc[1] / WS, M1Y = acc[2] / WS;
  const double M2X = acc[3] / WS, M2Y = acc[4] / WS;
  const double S1 = sqrt(2.0) / (acc[5] / WS + 1e-8);
  const double S2 = sqrt(2.0) / (acc[6] / WS + 1e-8);
  double M[45];
#pragma unroll
  for (int r = 0; r < 45; ++r) M[r] = acc[7 + r];
  solveF(M, S1, M1X, M1Y, S2, M2X, M2Y, outF);
}

// ============================================================
// Host launcher
// ============================================================
extern "C" void kernel_launch(void* const* d_in, const int* in_sizes, int n_in,
                              void* d_out, int out_size, void* d_ws, size_t ws_size,
                              hipStream_t stream) {
  const float* pts1 = (const float*)d_in[0];
  const float* pts2 = (const float*)d_in[1];
  const int* samples = (const int*)d_in[2];
  const int N = in_sizes[0] / 3;      // 16384
  const int iters = in_sizes[2] / 8;  // 4096

  // workspace layout
  double* acc = (double*)d_ws;                     // 52 doubles
  float* models = (float*)(acc + 52);              // iters*9
  float* ml = models + (size_t)iters * 9;          // iters
  float* ssum = ml + iters;                        // iters
  int* uniq = (int*)(ssum + iters);                // iters
  int* best = uniq + iters;                        // 1
  float* sx1 = (float*)(best + 1);                 // 6 SoA arrays of N
  float* sy1 = sx1 + N;
  float* sz1 = sy1 + N;
  float* sx2 = sz1 + N;
  float* sy2 = sx2 + N;
  float* sz2 = sy2 + N;

  float* outF = (float*)d_out;  // 9 floats (Mbest)
  float* outmask = outF + 9;    // N floats (0/1)

  hipMemsetAsync(acc, 0, 52 * sizeof(double), stream);
  transpose_soa<<<(N + 255) / 256, 256, 0, stream>>>(pts1, pts2, sx1, sy1, sz1,
                                                     sx2, sy2, sz2, N);
  fit_models<<<(iters + 63) / 64, 64, 0, stream>>>(pts1, pts2, samples, models,
                                                   uniq, iters);
  sampson_stats4<<<(iters + 3) / 4, 256, 0, stream>>>(sx1, sy1, sz1, sx2, sy2,
                                                      sz2, models, ml, ssum, N,
                                                      iters);
  select_best<<<1, 256, 0, stream>>>(ml, ssum, uniq, iters, best);
  write_mask<<<(N + 255) / 256, 256, 0, stream>>>(sx1, sy1, sz1, sx2, sy2, sz2,
                                                  models, best, outmask, N);
  ff_pass1<<<(N + 255) / 256, 256, 0, stream>>>(outmask, sx1, sy1, sx2, sy2, acc, N);
  ff_pass2<<<(N + 255) / 256, 256, 0, stream>>>(outmask, sx1, sy1, sx2, sy2, acc, N);
  ff_pass3<<<(N + 1023) / 1024, 256, 0, stream>>>(outmask, sx1, sy1, sz1, sx2,
                                                  sy2, sz2, acc, N);
  ff_solve<<<1, 64, 0, stream>>>(acc, outF);
}

// Round 3
// 261.981 us; speedup vs baseline: 1.5396x; 1.5396x over previous
//
#include <hip/hip_runtime.h>
#include <math.h>

// ============================================================
// Small dense linear algebra in double precision (per-thread).
// 9x9 symmetric stored packed lower-tri: M[i*(i+1)/2 + j], j<=i.
// NOTE: callers MUST have a VGPR budget >= ~256 (launch_bounds min-waves=1)
// or M[45] spills to scratch (R2: final_fit @76 VGPR = 126us of thrash).
// ============================================================

__device__ __forceinline__ void chol9(double* M) {
#pragma unroll
  for (int i = 0; i < 9; ++i) {
    const int ib = i * (i + 1) / 2;
#pragma unroll
    for (int j = 0; j <= i; ++j) {
      const int jb = j * (j + 1) / 2;
      double s = M[ib + j];
#pragma unroll
      for (int k = 0; k < j; ++k) s -= M[ib + k] * M[jb + k];
      if (j == i)
        M[ib + j] = sqrt(fmax(s, 1e-300));
      else
        M[ib + j] = s / M[jb + j];
    }
  }
}

__device__ __forceinline__ void cholsolve9(const double* L, double* x) {
#pragma unroll
  for (int i = 0; i < 9; ++i) {
    const int ib = i * (i + 1) / 2;
    double s = x[i];
#pragma unroll
    for (int k = 0; k < i; ++k) s -= L[ib + k] * x[k];
    x[i] = s / L[ib + i];
  }
#pragma unroll
  for (int i = 8; i >= 0; --i) {
    double s = x[i];
#pragma unroll
    for (int k = i + 1; k < 9; ++k) s -= L[k * (k + 1) / 2 + i] * x[k];
    x[i] = s / L[i * (i + 1) / 2 + i];
  }
}

// Smallest-eigenvalue eigenvector of symmetric 3x3 via cyclic Jacobi.
__device__ __forceinline__ void smallest_evec3(const double G[3][3], double v3[3]) {
  double a[3][3] = {{G[0][0], G[0][1], G[0][2]},
                    {G[1][0], G[1][1], G[1][2]},
                    {G[2][0], G[2][1], G[2][2]}};
  double V[3][3] = {{1, 0, 0}, {0, 1, 0}, {0, 0, 1}};
  for (int sweep = 0; sweep < 6; ++sweep) {
#pragma unroll
    for (int p = 0; p < 2; ++p) {
#pragma unroll
      for (int q = p + 1; q < 3; ++q) {
        double apq = a[p][q];
        if (fabs(apq) < 1e-300) continue;
        double tau = (a[q][q] - a[p][p]) / (2.0 * apq);
        double t = ((tau >= 0.0) ? 1.0 : -1.0) / (fabs(tau) + sqrt(1.0 + tau * tau));
        double c = 1.0 / sqrt(1.0 + t * t);
        double s = t * c;
#pragma unroll
        for (int k = 0; k < 3; ++k) {
          double akp = a[k][p], akq = a[k][q];
          a[k][p] = c * akp - s * akq;
          a[k][q] = s * akp + c * akq;
        }
#pragma unroll
        for (int k = 0; k < 3; ++k) {
          double apk = a[p][k], aqk = a[q][k];
          a[p][k] = c * apk - s * aqk;
          a[q][k] = s * apk + c * aqk;
        }
#pragma unroll
        for (int k = 0; k < 3; ++k) {
          double vkp = V[k][p], vkq = V[k][q];
          V[k][p] = c * vkp - s * vkq;
          V[k][q] = s * vkp + c * vkq;
        }
      }
    }
  }
  double mv = a[0][0];
  double v0 = V[0][0], v1 = V[1][0], v2 = V[2][0];
  if (a[1][1] < mv) { mv = a[1][1]; v0 = V[0][1]; v1 = V[1][1]; v2 = V[2][1]; }
  if (a[2][2] < mv) { mv = a[2][2]; v0 = V[0][2]; v1 = V[1][2]; v2 = V[2][2]; }
  v3[0] = v0; v3[1] = v1; v3[2] = v2;
}

__device__ __forceinline__ void solveF(double* M, double s1, double m1x, double m1y,
                                       double s2, double m2x, double m2y,
                                       float* out) {
  double tr = M[0] + M[2] + M[5] + M[9] + M[14] + M[20] + M[27] + M[35] + M[44];
  double shift = 1e-12 * tr;
  M[0] += shift; M[2] += shift; M[5] += shift; M[9] += shift; M[14] += shift;
  M[20] += shift; M[27] += shift; M[35] += shift; M[44] += shift;
  chol9(M);
  double x[9];
#pragma unroll
  for (int i = 0; i < 9; ++i) x[i] = 1.0;
  for (int t = 0; t < 3; ++t) {
    cholsolve9(M, x);
    double n = 0.0;
#pragma unroll
    for (int i = 0; i < 9; ++i) n += x[i] * x[i];
    n = 1.0 / sqrt(n);
#pragma unroll
    for (int i = 0; i < 9; ++i) x[i] *= n;
  }
  double F0[3][3] = {{x[0], x[1], x[2]}, {x[3], x[4], x[5]}, {x[6], x[7], x[8]}};
  double G[3][3];
#pragma unroll
  for (int i = 0; i < 3; ++i)
#pragma unroll
    for (int j = 0; j < 3; ++j)
      G[i][j] = F0[0][i] * F0[0][j] + F0[1][i] * F0[1][j] + F0[2][i] * F0[2][j];
  double v3[3];
  smallest_evec3(G, v3);
  double Fv[3];
#pragma unroll
  for (int i = 0; i < 3; ++i)
    Fv[i] = F0[i][0] * v3[0] + F0[i][1] * v3[1] + F0[i][2] * v3[2];
  double F2[3][3];
#pragma unroll
  for (int i = 0; i < 3; ++i)
#pragma unroll
    for (int j = 0; j < 3; ++j) F2[i][j] = F0[i][j] - Fv[i] * v3[j];
  double R[3][3];
#pragma unroll
  for (int j = 0; j < 3; ++j) {
    R[0][j] = s2 * F2[0][j];
    R[1][j] = s2 * F2[1][j];
    R[2][j] = -s2 * m2x * F2[0][j] - s2 * m2y * F2[1][j] + F2[2][j];
  }
  double Ff[3][3];
#pragma unroll
  for (int i = 0; i < 3; ++i) {
    Ff[i][0] = s1 * R[i][0];
    Ff[i][1] = s1 * R[i][1];
    Ff[i][2] = -s1 * m1x * R[i][0] - s1 * m1y * R[i][1] + R[i][2];
  }
  double inv = 1.0 / Ff[2][2];
#pragma unroll
  for (int i = 0; i < 3; ++i)
#pragma unroll
    for (int j = 0; j < 3; ++j) out[3 * i + j] = (float)(Ff[i][j] * inv);
}

// ============================================================
// Kernel 0: AoS -> packed float4 SoA (x,y,z,0 per point)
// ============================================================
__global__ __launch_bounds__(256) void transpose_soa(
    const float* __restrict__ p1, const float* __restrict__ p2,
    float4* __restrict__ P1, float4* __restrict__ P2, int N) {
  const int i = blockIdx.x * 256 + threadIdx.x;
  if (i >= N) return;
  P1[i] = make_float4(p1[3 * i], p1[3 * i + 1], p1[3 * i + 2], 0.f);
  P2[i] = make_float4(p2[3 * i], p2[3 * i + 1], p2[3 * i + 2], 0.f);
}

// ============================================================
// Kernel 1: one thread per RANSAC iteration. launch_bounds(64,1) so the
// f64 solver state (M[45] = 90 VGPRs + solver temps) stays in registers.
// ============================================================
__global__ __launch_bounds__(64, 1) void fit_models(
    const float* __restrict__ pts1, const float* __restrict__ pts2,
    const int* __restrict__ samples, float* __restrict__ models,
    int* __restrict__ uflag, int iters) {
  const int it = blockIdx.x * 64 + threadIdx.x;
  if (it >= iters) return;
  int idx[8];
#pragma unroll
  for (int k = 0; k < 8; ++k) idx[k] = samples[it * 8 + k];
  int u = 1;
#pragma unroll
  for (int a = 0; a < 8; ++a)
#pragma unroll
    for (int b = a + 1; b < 8; ++b)
      if (idx[a] == idx[b]) u = 0;
  uflag[it] = u;

  float X1[8], Y1[8], Z1[8], X2[8], Y2[8], Z2[8];
#pragma unroll
  for (int k = 0; k < 8; ++k) {
    const int j = idx[k];
    X1[k] = pts1[3 * j];     Y1[k] = pts1[3 * j + 1]; Z1[k] = pts1[3 * j + 2];
    X2[k] = pts2[3 * j];     Y2[k] = pts2[3 * j + 1]; Z2[k] = pts2[3 * j + 2];
  }
  double sx1 = 0, sy1 = 0, sx2 = 0, sy2 = 0;
#pragma unroll
  for (int k = 0; k < 8; ++k) {
    sx1 += (double)X1[k]; sy1 += (double)Y1[k];
    sx2 += (double)X2[k]; sy2 += (double)Y2[k];
  }
  const double m1x = sx1 / 8.0, m1y = sy1 / 8.0;
  const double m2x = sx2 / 8.0, m2y = sy2 / 8.0;
  double sd1 = 0, sd2 = 0;
#pragma unroll
  for (int k = 0; k < 8; ++k) {
    double dx1 = (double)X1[k] - m1x, dy1 = (double)Y1[k] - m1y;
    double dx2 = (double)X2[k] - m2x, dy2 = (double)Y2[k] - m2y;
    sd1 += sqrt(dx1 * dx1 + dy1 * dy1);
    sd2 += sqrt(dx2 * dx2 + dy2 * dy2);
  }
  const double s1 = sqrt(2.0) / (sd1 / 8.0 + 1e-8);
  const double s2 = sqrt(2.0) / (sd2 / 8.0 + 1e-8);

  double M[45];
#pragma unroll
  for (int r = 0; r < 45; ++r) M[r] = 0.0;
#pragma unroll
  for (int k = 0; k < 8; ++k) {
    const double z1 = (double)Z1[k], z2 = (double)Z2[k];
    const double p1x = s1 * ((double)X1[k] - m1x * z1);
    const double p1y = s1 * ((double)Y1[k] - m1y * z1);
    const double p2x = s2 * ((double)X2[k] - m2x * z2);
    const double p2y = s2 * ((double)Y2[k] - m2y * z2);
    const double a[9] = {p2x * p1x, p2x * p1y, p2x * z1,
                         p2y * p1x, p2y * p1y, p2y * z1,
                         z2 * p1x,  z2 * p1y,  z2 * z1};
#pragma unroll
    for (int i = 0; i < 9; ++i)
#pragma unroll
      for (int j = 0; j <= i; ++j) M[i * (i + 1) / 2 + j] += a[i] * a[j];
  }
  solveF(M, s1, m1x, m1y, s2, m2x, m2y, models + (size_t)it * 9);
}

// ============================================================
// Sampson error — named scalars only (no local arrays -> guaranteed VGPRs).
// Identical expression order to the passing R2 kernel.
// ============================================================
struct F9 {
  float f0, f1, f2, f3, f4, f5, f6, f7, f8;
};

__device__ __forceinline__ F9 loadF(const float* __restrict__ p) {
  F9 F;
  F.f0 = p[0]; F.f1 = p[1]; F.f2 = p[2];
  F.f3 = p[3]; F.f4 = p[4]; F.f5 = p[5];
  F.f6 = p[6]; F.f7 = p[7]; F.f8 = p[8];
  return F;
}

__device__ __forceinline__ float sampson_err(const F9 F, float x1, float y1,
                                             float z1, float x2, float y2,
                                             float z2) {
  float a0 = F.f0 * x1 + F.f1 * y1 + F.f2 * z1;
  float a1 = F.f3 * x1 + F.f4 * y1 + F.f5 * z1;
  float a2 = F.f6 * x1 + F.f7 * y1 + F.f8 * z1;
  float b0 = F.f0 * x2 + F.f3 * y2 + F.f6 * z2;
  float b1 = F.f1 * x2 + F.f4 * y2 + F.f7 * z2;
  float d = x2 * a0 + y2 * a1 + z2 * a2;
  float den = a0 * a0 + a1 * a1 + b0 * b0 + b1 * b1;
  return (d * d) / den;
}

__device__ __forceinline__ void samp_acc(const F9 F, float x1, float y1,
                                         float z1, float x2, float y2, float z2,
                                         float& cnt, float& ss) {
  float err = sampson_err(F, x1, y1, z1, x2, y2, z2);
  if (err <= 1.0f) {
    cnt += 1.0f;
    ss += sqrtf(err);
  }
}

// Kernel 2: 4 models per block over all N points. launch_bounds(256,4):
// VGPR cap 128 (need ~70) -> no spill, >=16 waves/CU.
__global__ __launch_bounds__(256, 4) void sampson_stats4(
    const float4* __restrict__ P1, const float4* __restrict__ P2,
    const float* __restrict__ models, float* __restrict__ ml,
    float* __restrict__ ssum, int N, int iters) {
  const int m0 = blockIdx.x * 4;
  const int c0 = min(m0 + 0, iters - 1), c1 = min(m0 + 1, iters - 1);
  const int c2 = min(m0 + 2, iters - 1), c3 = min(m0 + 3, iters - 1);
  const F9 Fa = loadF(models + (size_t)c0 * 9);
  const F9 Fb = loadF(models + (size_t)c1 * 9);
  const F9 Fc = loadF(models + (size_t)c2 * 9);
  const F9 Fd = loadF(models + (size_t)c3 * 9);
  float ca = 0, cb = 0, cc = 0, cd = 0;
  float sa = 0, sb = 0, sc_ = 0, sd = 0;
  for (int i = threadIdx.x; i < N; i += 256) {
    const float4 p = P1[i];
    const float4 q = P2[i];
    samp_acc(Fa, p.x, p.y, p.z, q.x, q.y, q.z, ca, sa);
    samp_acc(Fb, p.x, p.y, p.z, q.x, q.y, q.z, cb, sb);
    samp_acc(Fc, p.x, p.y, p.z, q.x, q.y, q.z, cc, sc_);
    samp_acc(Fd, p.x, p.y, p.z, q.x, q.y, q.z, cd, sd);
  }
  __shared__ float shc[4][4], shs[4][4];
  const int lane = threadIdx.x & 63, wv = threadIdx.x >> 6;
  float c4[4] = {ca, cb, cc, cd};
  float s4[4] = {sa, sb, sc_, sd};
#pragma unroll
  for (int m = 0; m < 4; ++m) {
    float c = c4[m], s = s4[m];
#pragma unroll
    for (int o = 32; o > 0; o >>= 1) {
      c += __shfl_down(c, o);
      s += __shfl_down(s, o);
    }
    if (lane == 0) { shc[wv][m] = c; shs[wv][m] = s; }
  }
  __syncthreads();
  if (threadIdx.x < 4 && m0 + threadIdx.x < iters) {
    const int m = threadIdx.x;
    ml[m0 + m] = shc[0][m] + shc[1][m] + shc[2][m] + shc[3][m];
    ssum[m0 + m] = shs[0][m] + shs[1][m] + shs[2][m] + shs[3][m];
  }
}

// ============================================================
// Kernel 3: scores + argmax (first-index tie-break like jnp.argmax)
// ============================================================
__global__ __launch_bounds__(256) void select_best(
    const float* __restrict__ ml, const float* __restrict__ ssum,
    const int* __restrict__ uniq, int iters, int* __restrict__ best) {
  const int tid = threadIdx.x;
  __shared__ float ra[256], rb[256];
  __shared__ int rid[256];
  float mlmax = 0.f, mnmax = -INFINITY;
  for (int i = tid; i < iters; i += 256) {
    if (uniq[i]) {
      float m = ml[i];
      mlmax = fmaxf(mlmax, m);
      float mean = (ssum[i] + 1e-8f) / (m + 1e-8f);
      mnmax = fmaxf(mnmax, mean);
    }
  }
  ra[tid] = mlmax;
  rb[tid] = mnmax;
  __syncthreads();
  for (int s = 128; s > 0; s >>= 1) {
    if (tid < s) {
      ra[tid] = fmaxf(ra[tid], ra[tid + s]);
      rb[tid] = fmaxf(rb[tid], rb[tid + s]);
    }
    __syncthreads();
  }
  const float MLMAX = ra[0];
  const float MNMAX = rb[0];
  __syncthreads();
  float bsc = -INFINITY;
  int bid = 0x7FFFFFFF;
  for (int i = tid; i < iters; i += 256) {
    float sc = -INFINITY;
    float m = ml[i];
    float mean = (ssum[i] + 1e-8f) / (m + 1e-8f);
    if (uniq[i]) sc = 0.5f * (m / MLMAX) + 0.5f * (1.0f - mean / MNMAX);
    if (sc > bsc || (sc == bsc && i < bid)) { bsc = sc; bid = i; }
  }
  ra[tid] = bsc;
  rid[tid] = bid;
  __syncthreads();
  for (int s = 128; s > 0; s >>= 1) {
    if (tid < s) {
      if (ra[tid + s] > ra[tid] ||
          (ra[tid + s] == ra[tid] && rid[tid + s] < rid[tid])) {
        ra[tid] = ra[tid + s];
        rid[tid] = rid[tid + s];
      }
    }
    __syncthreads();
  }
  if (tid == 0) best[0] = rid[0];
}

// ============================================================
// Kernel 4: best mask -> d_out[9..], fused with final-fit pass 1
// acc: [0]=sw [1]=sx1 [2]=sy1 [3]=sx2 [4]=sy2 [5]=sd1 [6]=sd2 [7..51]=AtA
// ============================================================
__global__ __launch_bounds__(256) void mask_pass1(
    const float4* __restrict__ P1, const float4* __restrict__ P2,
    const float* __restrict__ models, const int* __restrict__ best,
    float* __restrict__ outmask, double* __restrict__ acc, int N) {
  const int i = blockIdx.x * 256 + threadIdx.x;
  double w = 0, a = 0, b = 0, c = 0, d = 0;
  if (i < N) {
    const F9 F = loadF(models + (size_t)best[0] * 9);
    const float4 p = P1[i];
    const float4 q = P2[i];
    float err = sampson_err(F, p.x, p.y, p.z, q.x, q.y, q.z);
    float m = (err <= 1.0f) ? 1.0f : 0.0f;
    outmask[i] = m;
    w = (double)m;
    a = w * (double)p.x;
    b = w * (double)p.y;
    c = w * (double)q.x;
    d = w * (double)q.y;
  }
#pragma unroll
  for (int o = 32; o > 0; o >>= 1) {
    w += __shfl_down(w, o); a += __shfl_down(a, o); b += __shfl_down(b, o);
    c += __shfl_down(c, o); d += __shfl_down(d, o);
  }
  if ((threadIdx.x & 63) == 0) {
    atomicAdd(&acc[0], w); atomicAdd(&acc[1], a); atomicAdd(&acc[2], b);
    atomicAdd(&acc[3], c); atomicAdd(&acc[4], d);
  }
}

__global__ __launch_bounds__(256) void ff_pass2(
    const float* __restrict__ mask, const float4* __restrict__ P1,
    const float4* __restrict__ P2, double* __restrict__ acc, int N) {
  const double WS = acc[0];
  const double M1X = acc[1] / WS, M1Y = acc[2] / WS;
  const double M2X = acc[3] / WS, M2Y = acc[4] / WS;
  const int i = blockIdx.x * 256 + threadIdx.x;
  double s1 = 0, s2 = 0;
  if (i < N) {
    double w = (double)mask[i];
    if (w != 0.0) {
      const float4 p = P1[i];
      const float4 q = P2[i];
      double dx1 = (double)p.x - M1X, dy1 = (double)p.y - M1Y;
      double dx2 = (double)q.x - M2X, dy2 = (double)q.y - M2Y;
      s1 = w * sqrt(dx1 * dx1 + dy1 * dy1);
      s2 = w * sqrt(dx2 * dx2 + dy2 * dy2);
    }
  }
#pragma unroll
  for (int o = 32; o > 0; o >>= 1) {
    s1 += __shfl_down(s1, o);
    s2 += __shfl_down(s2, o);
  }
  if ((threadIdx.x & 63) == 0) {
    atomicAdd(&acc[5], s1);
    atomicAdd(&acc[6], s2);
  }
}

// A[45] doubles per thread -> needs ~130 VGPRs; launch_bounds(256,1) = cap 512.
__global__ __launch_bounds__(256, 1) void ff_pass3(
    const float* __restrict__ mask, const float4* __restrict__ P1,
    const float4* __restrict__ P2, double* __restrict__ acc, int N) {
  const double WS = acc[0];
  const double M1X = acc[1] / WS, M1Y = acc[2] / WS;
  const double M2X = acc[3] / WS, M2Y = acc[4] / WS;
  const double S1 = sqrt(2.0) / (acc[5] / WS + 1e-8);
  const double S2 = sqrt(2.0) / (acc[6] / WS + 1e-8);
  double A[45];
#pragma unroll
  for (int r = 0; r < 45; ++r) A[r] = 0.0;
#pragma unroll
  for (int k = 0; k < 4; ++k) {
    const int i = blockIdx.x * 1024 + k * 256 + threadIdx.x;
    if (i < N) {
      const double w = (double)mask[i];
      if (w != 0.0) {
        const float4 p = P1[i];
        const float4 q = P2[i];
        const double zz1 = (double)p.z, zz2 = (double)q.z;
        const double p1x = S1 * ((double)p.x - M1X * zz1);
        const double p1y = S1 * ((double)p.y - M1Y * zz1);
        const double p2x = S2 * ((double)q.x - M2X * zz2);
        const double p2y = S2 * ((double)q.y - M2Y * zz2);
        const double a[9] = {p2x * p1x, p2x * p1y, p2x * zz1,
                             p2y * p1x, p2y * p1y, p2y * zz1,
                             zz2 * p1x, zz2 * p1y, zz2 * zz1};
        const double ww = w * w;
#pragma unroll
        for (int ii = 0; ii < 9; ++ii)
#pragma unroll
          for (int jj = 0; jj <= ii; ++jj)
            A[ii * (ii + 1) / 2 + jj] += ww * a[ii] * a[jj];
      }
    }
  }
  const int lane = threadIdx.x & 63;
#pragma unroll
  for (int r = 0; r < 45; ++r) {
    double v = A[r];
#pragma unroll
    for (int o = 32; o > 0; o >>= 1) v += __shfl_down(v, o);
    if (lane == 0) atomicAdd(&acc[7 + r], v);
  }
}

__global__ __launch_bounds__(64, 1) void ff_solve(const double* __restrict__ acc,
                                                  float* __restrict__ outF) {
  if (threadIdx.x != 0 || blockIdx.x != 0) return;
  const double WS = acc[0];
  const double M1X = acc[1] / WS, M1Y = acc[2] / WS;
  const double M2X = acc[3] / WS, M2Y = acc[4] / WS;
  const double S1 = sqrt(2.0) / (acc[5] / WS + 1e-8);
  const double S2 = sqrt(2.0) / (acc[6] / WS + 1e-8);
  double M[45];
#pragma unroll
  for (int r = 0; r < 45; ++r) M[r] = acc[7 + r];
  solveF(M, S1, M1X, M1Y, S2, M2X, M2Y, outF);
}

// ============================================================
// Host launcher
// ============================================================
extern "C" void kernel_launch(void* const* d_in, const int* in_sizes, int n_in,
                              void* d_out, int out_size, void* d_ws, size_t ws_size,
                              hipStream_t stream) {
  const float* pts1 = (const float*)d_in[0];
  const float* pts2 = (const float*)d_in[1];
  const int* samples = (const int*)d_in[2];
  const int N = in_sizes[0] / 3;      // 16384
  const int iters = in_sizes[2] / 8;  // 4096

  // workspace layout
  double* acc = (double*)d_ws;                     // 52 doubles
  float* models = (float*)(acc + 52);              // iters*9
  float* ml = models + (size_t)iters * 9;          // iters
  float* ssum = ml + iters;                        // iters
  int* uniq = (int*)(ssum + iters);                // iters
  int* best = uniq + iters;                        // 1 (+3 pad to 16B)
  float4* P1 = (float4*)(best + 4);                // N float4
  float4* P2 = P1 + N;                             // N float4

  float* outF = (float*)d_out;  // 9 floats (Mbest)
  float* outmask = outF + 9;    // N floats (0/1)

  hipMemsetAsync(acc, 0, 52 * sizeof(double), stream);
  transpose_soa<<<(N + 255) / 256, 256, 0, stream>>>(pts1, pts2, P1, P2, N);
  fit_models<<<(iters + 63) / 64, 64, 0, stream>>>(pts1, pts2, samples, models,
                                                   uniq, iters);
  sampson_stats4<<<(iters + 3) / 4, 256, 0, stream>>>(P1, P2, models, ml, ssum,
                                                      N, iters);
  select_best<<<1, 256, 0, stream>>>(ml, ssum, uniq, iters, best);
  mask_pass1<<<(N + 255) / 256, 256, 0, stream>>>(P1, P2, models, best, outmask,
                                                  acc, N);
  ff_pass2<<<(N + 255) / 256, 256, 0, stream>>>(outmask, P1, P2, acc, N);
  ff_pass3<<<(N + 1023) / 1024, 256, 0, stream>>>(outmask, P1, P2, acc, N);
  ff_solve<<<1, 64, 0, stream>>>(acc, outF);
}